// Round 4
// baseline (29.694 us; speedup 1.0000x reference)
//
#include <hip/hip_runtime.h>
#include <hip/hip_bf16.h>

#define BB 4096
#define CC 256
#define DD 512
#define SS 8

#define BM 64
#define BN 64
#define BK 64
#define NCT (DD / BN)   // 8 col tiles
#define MAXT 71         // max possible tiles: 64 + 7

typedef __attribute__((ext_vector_type(4))) float f32x4;
typedef __attribute__((ext_vector_type(8))) short s16x8;

// RNE float -> bf16 bits
static __device__ inline short f2bf(float f) {
    unsigned int u = __float_as_uint(f);
    u = u + 0x7FFFu + ((u >> 16) & 1u);
    return (short)(u >> 16);
}

__global__ __launch_bounds__(256) void fused_kernel(
    const float* __restrict__ x, const int* __restrict__ subj,
    const float* __restrict__ w, const float* __restrict__ bias,
    float* __restrict__ out)
{
    const int tid = threadIdx.x;
    const int lane = tid & 63;
    const int wv = tid >> 6;                       // wave 0..3
    const unsigned long long lt = (1ull << lane) - 1ull;

    __shared__ int wcnt[16][4][SS];                // per-(chunk,wave,subject) counts
    __shared__ int cpre[16][SS];                   // chunk-level exclusive prefix
    __shared__ int hist[SS];
    __shared__ int rows_l[BM];
    __shared__ __align__(16) short As[BM * BK];    // [row][k], XOR-swizzled (8KB)
    __shared__ __align__(16) short Bs[BK / 8][BN][8]; // k-blocked (8KB)

    // ---- load subject ids: 16 chunks of 256 consecutive rows
    int sl[16];
#pragma unroll
    for (int i = 0; i < 16; ++i) sl[i] = subj[tid + i * 256];

    // ---- pass 1: ballot counts per (chunk, wave, subject) — no atomics
#pragma unroll
    for (int i = 0; i < 16; ++i) {
        int sr = sl[i];
        int pc = 0;
#pragma unroll
        for (int v = 0; v < SS; ++v) {
            unsigned long long mv = __ballot(sr == v);
            if (lane == v) pc = __popcll(mv);
        }
        if (lane < SS) wcnt[i][wv][lane] = pc;
    }
    __syncthreads();

    // ---- chunk exclusive prefix + per-subject totals (8 threads, 16 steps)
    if (tid < SS) {
        int run = 0;
        for (int i = 0; i < 16; ++i) {
            int c = wcnt[i][0][tid] + wcnt[i][1][tid] + wcnt[i][2][tid] + wcnt[i][3][tid];
            cpre[i][tid] = run;
            run += c;
        }
        hist[tid] = run;
    }
    __syncthreads();

    // ---- tile mapping (identical on every thread)
    int h[SS];
#pragma unroll
    for (int v = 0; v < SS; ++v) h[v] = hist[v];
    const int tile = blockIdx.x >> 3;
    int s = -1, t = 0, acc_t = 0;
#pragma unroll
    for (int v = 0; v < SS; ++v) {
        int tv = (h[v] + BM - 1) >> 6;
        if (s < 0 && tile < acc_t + tv) { s = v; t = tile - acc_t; }
        acc_t += tv;
    }
    if (s < 0) return;                              // beyond dynamic tile count (uniform)
    int m_valid = h[s] - t * BM; if (m_valid > BM) m_valid = BM;

    // ---- pass 2: global stable ranks -> this tile's row list
    if (tid < BM) rows_l[tid] = -1;
    __syncthreads();
#pragma unroll
    for (int i = 0; i < 16; ++i) {
        int sr = sl[i];
        unsigned long long same = 0;
#pragma unroll
        for (int v = 0; v < SS; ++v) {
            unsigned long long mv = __ballot(sr == v);
            if (sr == v) same = mv;
        }
        if (sr == s) {
            int rank = cpre[i][s] + __popcll(same & lt);
            for (int w2 = 0; w2 < wv; ++w2) rank += wcnt[i][w2][s];
            int p = rank - t * BM;
            if (p >= 0 && p < BM) rows_l[p] = tid + i * 256;
        }
    }
    __syncthreads();

    // ---- GEMM
    const int bcol = (blockIdx.x & 7) * BN;
    const int wm = wv & 1, wn = wv >> 1;
    const int lr = lane & 15, lg = lane >> 4;

    f32x4 acc[2][2];
#pragma unroll
    for (int mf = 0; mf < 2; ++mf)
#pragma unroll
        for (int nf = 0; nf < 2; ++nf)
            acc[mf][nf] = (f32x4)0.0f;

    const int ar = tid >> 2;           // A row (4 threads/row)
    const int a4 = (tid & 3) * 16;     // float offset within 64-float K-chunk
    const int grow = rows_l[ar];
    const float* xp = x + (size_t)(grow < 0 ? 0 : grow) * CC + a4;
    const float* wb = w + (size_t)s * CC * DD + bcol;

    for (int ks = 0; ks < CC / BK; ++ks) {
        // ---- stage A: fp32 x -> bf16, swizzled LDS
#pragma unroll
        for (int i = 0; i < 2; ++i) {
            s16x8 p = (s16x8)(short)0;
            if (grow >= 0) {
                f32x4 v0 = *reinterpret_cast<const f32x4*>(xp + ks * BK + i * 8);
                f32x4 v1 = *reinterpret_cast<const f32x4*>(xp + ks * BK + i * 8 + 4);
                p[0] = f2bf(v0[0]); p[1] = f2bf(v0[1]); p[2] = f2bf(v0[2]); p[3] = f2bf(v0[3]);
                p[4] = f2bf(v1[0]); p[5] = f2bf(v1[1]); p[6] = f2bf(v1[2]); p[7] = f2bf(v1[3]);
            }
            int c = (tid & 3) * 2 + i;
            *reinterpret_cast<s16x8*>(reinterpret_cast<char*>(As)
                + ar * 128 + ((c * 16) ^ ((ar & 7) << 4))) = p;
        }
        // ---- stage B: fp32 w -> bf16, k-blocked LDS (coalesced per-e across lanes)
#pragma unroll
        for (int i = 0; i < 2; ++i) {
            int kb = wv + i * 4;
            const float* wp = wb + (size_t)(ks * BK + kb * 8) * DD + lane;
            s16x8 p;
#pragma unroll
            for (int e = 0; e < 8; ++e) p[e] = f2bf(wp[(size_t)e * DD]);
            *reinterpret_cast<s16x8*>(&Bs[kb][lane][0]) = p;
        }
        __syncthreads();

        s16x8 af[2][2], bfr[2][2];
#pragma unroll
        for (int mf = 0; mf < 2; ++mf) {
            int row = wm * 32 + mf * 16 + lr;
#pragma unroll
            for (int kh = 0; kh < 2; ++kh) {
                int kf2 = (kh * 32 + lg * 8) * 2;
                af[mf][kh] = *reinterpret_cast<s16x8*>(reinterpret_cast<char*>(As)
                    + row * 128 + (kf2 ^ ((row & 7) << 4)));
            }
        }
#pragma unroll
        for (int nf = 0; nf < 2; ++nf) {
            int n = wn * 32 + nf * 16 + lr;
#pragma unroll
            for (int kh = 0; kh < 2; ++kh)
                bfr[nf][kh] = *reinterpret_cast<s16x8*>(&Bs[kh * 4 + lg][n][0]);
        }
#pragma unroll
        for (int mf = 0; mf < 2; ++mf)
#pragma unroll
            for (int nf = 0; nf < 2; ++nf)
#pragma unroll
                for (int kh = 0; kh < 2; ++kh)
                    acc[mf][nf] = __builtin_amdgcn_mfma_f32_16x16x32_bf16(
                        af[mf][kh], bfr[nf][kh], acc[mf][nf], 0, 0, 0);
        __syncthreads();
    }

    // ---- epilogue: + bias, scatter rows back
#pragma unroll
    for (int nf = 0; nf < 2; ++nf) {
        int col = bcol + wn * 32 + nf * 16 + lr;
        float bv = bias[s * DD + col];
#pragma unroll
        for (int mf = 0; mf < 2; ++mf) {
            int rl0 = wm * 32 + mf * 16 + lg * 4;
#pragma unroll
            for (int r = 0; r < 4; ++r) {
                int rl = rl0 + r;
                if (rl < m_valid) {
                    int g = rows_l[rl];
                    out[(size_t)g * DD + col] = acc[mf][nf][r] + bv;
                }
            }
        }
    }
}

extern "C" void kernel_launch(void* const* d_in, const int* in_sizes, int n_in,
                              void* d_out, int out_size, void* d_ws, size_t ws_size,
                              hipStream_t stream) {
    const float* x        = (const float*)d_in[0];
    const int*   subjects = (const int*)d_in[1];
    const float* weights  = (const float*)d_in[2];
    const float* bias     = (const float*)d_in[3];
    float* out = (float*)d_out;

    fused_kernel<<<MAXT * NCT, 256, 0, stream>>>(x, subjects, weights, bias, out);
}

// Round 5
// 23.170 us; speedup vs baseline: 1.2816x; 1.2816x over previous
//
#include <hip/hip_runtime.h>
#include <hip/hip_bf16.h>

#define BB 4096
#define CC 256
#define DD 512
#define SS 8

#define BM 64
#define BN 64
#define BK 64

typedef __attribute__((ext_vector_type(4))) float f32x4;
typedef __attribute__((ext_vector_type(8))) short s16x8;

// RNE float -> bf16 bits
static __device__ inline short f2bf(float f) {
    unsigned int u = __float_as_uint(f);
    u = u + 0x7FFFu + ((u >> 16) & 1u);
    return (short)(u >> 16);
}

// ws layout:
//   meta[0..7]  : per-subject counts
//   meta[8..15] : per-subject exclusive offsets
//   rows[4096]  : compacted row indices, grouped by subject
//   w_bf        : [s][kb=32][n=512][8] bf16
// prep grid = 520: block 0 = binning; blocks 1..7 idle; blocks 8..519 w-cvt
// with subject = blockIdx & 7  (XCD affinity: blockIdx % 8 -> XCD round-robin)
__global__ __launch_bounds__(256) void prep_kernel(
    const float* __restrict__ w, const int* __restrict__ subj,
    int* __restrict__ meta, int* __restrict__ rows, short* __restrict__ w_bf)
{
    const int tid = threadIdx.x;
    if (blockIdx.x == 0) {
        // ---- binning: ballot-based histogram + placement
        __shared__ int hist[SS], cur[SS];
        const int lane = tid & 63;
        const unsigned long long lt = (1ull << lane) - 1ull;
        if (tid < SS) hist[tid] = 0;
        __syncthreads();
        int sl[16];
#pragma unroll
        for (int i = 0; i < 16; ++i) sl[i] = subj[tid + i * 256];
#pragma unroll
        for (int i = 0; i < 16; ++i) {
            int s = sl[i];
            unsigned long long same = 0;
#pragma unroll
            for (int v = 0; v < SS; ++v) {
                unsigned long long mv = __ballot(s == v);
                if (s == v) same = mv;
            }
            int leader = __builtin_ctzll(same);
            if (lane == leader) atomicAdd(&hist[s], __popcll(same));
        }
        __syncthreads();
        if (tid == 0) {
            int o = 0;
            for (int v = 0; v < SS; ++v) {
                int c = hist[v];
                meta[v] = c; meta[SS + v] = o; cur[v] = o; o += c;
            }
        }
        __syncthreads();
#pragma unroll
        for (int i = 0; i < 16; ++i) {
            int s = sl[i];
            unsigned long long same = 0;
#pragma unroll
            for (int v = 0; v < SS; ++v) {
                unsigned long long mv = __ballot(s == v);
                if (s == v) same = mv;
            }
            int leader = __builtin_ctzll(same);
            int rank = __popcll(same & lt);
            int base = 0;
            if (lane == leader) base = atomicAdd(&cur[s], __popcll(same));
            base = __shfl(base, leader);
            rows[base + rank] = tid + i * 256;
        }
    } else if (blockIdx.x >= 8) {
        // ---- w -> bf16, k-blocked [s][kb][n][8]; subject pinned to XCD
        int j = blockIdx.x - 8;                // [0, 512)
        int s = j & 7, c = j >> 3;             // chunk c in [0,64)
        int ul = c * 256 + tid;                // [0, 16384) within subject
        int n = ul & 511, kb = ul >> 9;
        const float* wp = w + ((size_t)(s * CC + kb * 8)) * DD + n;
        s16x8 p;
#pragma unroll
        for (int e = 0; e < 8; ++e) p[e] = f2bf(wp[(size_t)e * DD]);
        *reinterpret_cast<s16x8*>(w_bf + ((size_t)s * 16384 + ul) * 8) = p;
    }
}

// gemm grid = 1024 flat: s = bid&7 (XCD affinity), rt = (bid>>3)&15, ct = bid>>7
__global__ __launch_bounds__(256) void gemm_kernel(
    const float* __restrict__ x, const short* __restrict__ w_bf,
    const float* __restrict__ bias, const int* __restrict__ meta,
    const int* __restrict__ rows, float* __restrict__ out)
{
    const int s  = blockIdx.x & 7;
    const int rt = (blockIdx.x >> 3) & 15;
    const int ct = blockIdx.x >> 7;
    const int n_s = meta[s];
    if (rt * BM >= n_s) return;                // uniform across block
    const int off = meta[SS + s];
    int m_valid = n_s - rt * BM; if (m_valid > BM) m_valid = BM;

    __shared__ __align__(16) short As[BM * BK];       // [row][k], XOR-swizzled (8KB)
    __shared__ __align__(16) short Bs[BK / 8][BN][8]; // k-blocked (8KB)
    __shared__ int rows_l[BM];

    const int tid = threadIdx.x;
    if (tid < BM) {
        int idx = rt * BM + tid;
        rows_l[tid] = (idx < n_s) ? rows[off + idx] : -1;
    }
    __syncthreads();

    const int bcol = ct * BN;
    const int lane = tid & 63, wid = tid >> 6;
    const int wm = wid & 1, wn = wid >> 1;
    const int lr = lane & 15, lg = lane >> 4;

    f32x4 acc[2][2];
#pragma unroll
    for (int mf = 0; mf < 2; ++mf)
#pragma unroll
        for (int nf = 0; nf < 2; ++nf)
            acc[mf][nf] = (f32x4)0.0f;

    const int ar = tid >> 2;           // A row (4 threads/row)
    const int a4 = (tid & 3) * 16;     // float offset within 64-float K-chunk
    const int grow = rows_l[ar];
    const float* xp = x + (size_t)(grow < 0 ? 0 : grow) * CC + a4;
    const short* wsrc = w_bf + ((size_t)(s * 32) * 512 + bcol) * 8;

    for (int ks = 0; ks < CC / BK; ++ks) {
        // ---- stage A: fp32 x -> bf16, swizzled LDS (inline conversion)
#pragma unroll
        for (int i = 0; i < 2; ++i) {
            s16x8 p = (s16x8)(short)0;
            if (grow >= 0) {
                f32x4 v0 = *reinterpret_cast<const f32x4*>(xp + ks * BK + i * 8);
                f32x4 v1 = *reinterpret_cast<const f32x4*>(xp + ks * BK + i * 8 + 4);
                p[0] = f2bf(v0[0]); p[1] = f2bf(v0[1]); p[2] = f2bf(v0[2]); p[3] = f2bf(v0[3]);
                p[4] = f2bf(v1[0]); p[5] = f2bf(v1[1]); p[6] = f2bf(v1[2]); p[7] = f2bf(v1[3]);
            }
            int c = (tid & 3) * 2 + i;
            *reinterpret_cast<s16x8*>(reinterpret_cast<char*>(As)
                + ar * 128 + ((c * 16) ^ ((ar & 7) << 4))) = p;
        }
        // ---- stage B: straight 16B copies from k-blocked w_bf
#pragma unroll
        for (int i = 0; i < 2; ++i) {
            int ch = tid + i * 256;
            int kb = ch >> 6, nn = ch & 63;
            *reinterpret_cast<s16x8*>(&Bs[kb][nn][0]) =
                *reinterpret_cast<const s16x8*>(wsrc + ((size_t)(ks * 8 + kb) * 512 + nn) * 8);
        }
        __syncthreads();

        s16x8 af[2][2], bfr[2][2];
#pragma unroll
        for (int mf = 0; mf < 2; ++mf) {
            int row = wm * 32 + mf * 16 + lr;
#pragma unroll
            for (int kh = 0; kh < 2; ++kh) {
                int kf2 = (kh * 32 + lg * 8) * 2;
                af[mf][kh] = *reinterpret_cast<s16x8*>(reinterpret_cast<char*>(As)
                    + row * 128 + (kf2 ^ ((row & 7) << 4)));
            }
        }
#pragma unroll
        for (int nf = 0; nf < 2; ++nf) {
            int n = wn * 32 + nf * 16 + lr;
#pragma unroll
            for (int kh = 0; kh < 2; ++kh)
                bfr[nf][kh] = *reinterpret_cast<s16x8*>(&Bs[kh * 4 + lg][n][0]);
        }
#pragma unroll
        for (int mf = 0; mf < 2; ++mf)
#pragma unroll
            for (int nf = 0; nf < 2; ++nf)
#pragma unroll
                for (int kh = 0; kh < 2; ++kh)
                    acc[mf][nf] = __builtin_amdgcn_mfma_f32_16x16x32_bf16(
                        af[mf][kh], bfr[nf][kh], acc[mf][nf], 0, 0, 0);
        __syncthreads();
    }

    // ---- epilogue: + bias, scatter rows back
#pragma unroll
    for (int nf = 0; nf < 2; ++nf) {
        int col = bcol + wn * 32 + nf * 16 + lr;
        float bv = bias[s * DD + col];
#pragma unroll
        for (int mf = 0; mf < 2; ++mf) {
            int rl0 = wm * 32 + mf * 16 + lg * 4;
#pragma unroll
            for (int r = 0; r < 4; ++r) {
                int rl = rl0 + r;
                if (rl < m_valid) {
                    int g = rows_l[rl];
                    out[(size_t)g * DD + col] = acc[mf][nf][r] + bv;
                }
            }
        }
    }
}

extern "C" void kernel_launch(void* const* d_in, const int* in_sizes, int n_in,
                              void* d_out, int out_size, void* d_ws, size_t ws_size,
                              hipStream_t stream) {
    const float* x        = (const float*)d_in[0];
    const int*   subjects = (const int*)d_in[1];
    const float* weights  = (const float*)d_in[2];
    const float* bias     = (const float*)d_in[3];
    float* out = (float*)d_out;

    int* meta  = (int*)d_ws;
    int* rows  = meta + 128;
    short* w_bf = (short*)(rows + BB);          // 2 MB

    prep_kernel<<<520, 256, 0, stream>>>(weights, subjects, meta, rows, w_bf);
    gemm_kernel<<<1024, 256, 0, stream>>>(x, w_bf, bias, meta, rows, out);
}